// Round 1
// baseline (318.483 us; speedup 1.0000x reference)
//
#include <hip/hip_runtime.h>

#define BS 16
#define NH 16
#define LQ 4096
#define DH 32

constexpr int SPLIT = 8;
constexpr int SCHUNK = LQ / SPLIT;          // 512
constexpr size_t OUT_ELEMS = (size_t)BS * NH * LQ * DH;   // 33,554,432
constexpr int WELEMS_PER_BH = DH * DH;      // 1024
constexpr int HDE = NH * DH * DH;           // 16384

// ---------------- Kernel A: partial K@V over an s-chunk ----------------
// grid: BS*NH*SPLIT blocks, 256 threads. part[p][bh][d][e] (8 MB in ws).
__global__ __launch_bounds__(256) void kv_partial(const float* __restrict__ k,
                                                  const float* __restrict__ v,
                                                  float* __restrict__ part) {
    int blk = blockIdx.x;
    int p   = blk & (SPLIT - 1);
    int bh  = blk / SPLIT;                  // 0..255
    int tid = threadIdx.x;
    int d   = tid >> 3;                     // 0..31
    int eg  = tid & 7;                      // float4 column group, e0 = eg*4

    const float* krow  = k + ((size_t)bh * DH + d) * LQ + (size_t)p * SCHUNK;
    const float* vbase = v + ((size_t)bh * LQ + (size_t)p * SCHUNK) * DH + eg * 4;

    float4 acc = make_float4(0.f, 0.f, 0.f, 0.f);
#pragma unroll 2
    for (int s = 0; s < SCHUNK; s += 4) {
        float4 kq = *(const float4*)(krow + s);
        float4 v0 = *(const float4*)(vbase + (size_t)(s + 0) * DH);
        float4 v1 = *(const float4*)(vbase + (size_t)(s + 1) * DH);
        float4 v2 = *(const float4*)(vbase + (size_t)(s + 2) * DH);
        float4 v3 = *(const float4*)(vbase + (size_t)(s + 3) * DH);

        acc.x = fmaf(kq.x, v0.x, acc.x);
        acc.x = fmaf(kq.y, v1.x, acc.x);
        acc.x = fmaf(kq.z, v2.x, acc.x);
        acc.x = fmaf(kq.w, v3.x, acc.x);

        acc.y = fmaf(kq.x, v0.y, acc.y);
        acc.y = fmaf(kq.y, v1.y, acc.y);
        acc.y = fmaf(kq.z, v2.y, acc.y);
        acc.y = fmaf(kq.w, v3.y, acc.y);

        acc.z = fmaf(kq.x, v0.z, acc.z);
        acc.z = fmaf(kq.y, v1.z, acc.z);
        acc.z = fmaf(kq.z, v2.z, acc.z);
        acc.z = fmaf(kq.w, v3.z, acc.z);

        acc.w = fmaf(kq.x, v0.w, acc.w);
        acc.w = fmaf(kq.y, v1.w, acc.w);
        acc.w = fmaf(kq.z, v2.w, acc.w);
        acc.w = fmaf(kq.w, v3.w, acc.w);
    }

    float* dst = part + ((size_t)p * (BS * NH) + bh) * WELEMS_PER_BH + d * DH + eg * 4;
    *(float4*)dst = acc;
}

// ---------------- Kernel B: reduce partials + softmax over batch axis ----------------
// grid: HDE/256 = 64 blocks. thread idx = h*1024 + d*32 + e. Writes weights[b][h][d][e].
__global__ __launch_bounds__(256) void softmax_b(const float* __restrict__ part,
                                                 float* __restrict__ wts) {
    int idx = blockIdx.x * 256 + threadIdx.x;     // 0..16383

    float sc[BS];
#pragma unroll
    for (int b = 0; b < BS; ++b) {
        float s = 0.f;
#pragma unroll
        for (int p = 0; p < SPLIT; ++p) {
            s += part[(((size_t)p * BS * NH + (size_t)b * NH) << 10) + idx];
        }
        sc[b] = s * (1.0f / 64.0f);               // / sqrt(4096)
    }

    float m = sc[0];
#pragma unroll
    for (int b = 1; b < BS; ++b) m = fmaxf(m, sc[b]);
    float sum = 0.f;
#pragma unroll
    for (int b = 0; b < BS; ++b) { sc[b] = __expf(sc[b] - m); sum += sc[b]; }
    float inv = 1.0f / sum;
#pragma unroll
    for (int b = 0; b < BS; ++b) {
        wts[(size_t)b * HDE + idx] = sc[b] * inv;
    }
}

// ---------------- Kernel C: out = Q @ W ----------------
// grid: BS*NH*(LQ/128) = 8192 blocks, 256 threads; W column-block in registers.
__global__ __launch_bounds__(256) void qw(const float* __restrict__ q,
                                          const float* __restrict__ wts,
                                          float* __restrict__ out) {
    int blk  = blockIdx.x;
    int bh   = blk >> 5;                    // /32
    int lt   = blk & 31;                    // 128-row tile
    int tid  = threadIdx.x;
    int lsub = tid >> 3;                    // 0..31
    int eg   = tid & 7;

    // W fragment: column block eg -> 32 x float4 in registers
    float4 Wf[32];
    const float* wbase = wts + (size_t)bh * WELEMS_PER_BH + eg * 4;
#pragma unroll
    for (int d = 0; d < 32; ++d) Wf[d] = *(const float4*)(wbase + d * DH);

    const float* qbase = q   + ((size_t)bh * LQ + (size_t)lt * 128) * DH;
    float*       obase = out + ((size_t)bh * LQ + (size_t)lt * 128) * DH;

#pragma unroll
    for (int r = 0; r < 4; ++r) {
        int l = lsub + r * 32;
        const float* qrow = qbase + (size_t)l * DH;
        float4 acc = make_float4(0.f, 0.f, 0.f, 0.f);
#pragma unroll
        for (int d4 = 0; d4 < 32; d4 += 4) {
            float4 qv = *(const float4*)(qrow + d4);
            acc.x = fmaf(qv.x, Wf[d4 + 0].x, acc.x);
            acc.x = fmaf(qv.y, Wf[d4 + 1].x, acc.x);
            acc.x = fmaf(qv.z, Wf[d4 + 2].x, acc.x);
            acc.x = fmaf(qv.w, Wf[d4 + 3].x, acc.x);

            acc.y = fmaf(qv.x, Wf[d4 + 0].y, acc.y);
            acc.y = fmaf(qv.y, Wf[d4 + 1].y, acc.y);
            acc.y = fmaf(qv.z, Wf[d4 + 2].y, acc.y);
            acc.y = fmaf(qv.w, Wf[d4 + 3].y, acc.y);

            acc.z = fmaf(qv.x, Wf[d4 + 0].z, acc.z);
            acc.z = fmaf(qv.y, Wf[d4 + 1].z, acc.z);
            acc.z = fmaf(qv.z, Wf[d4 + 2].z, acc.z);
            acc.z = fmaf(qv.w, Wf[d4 + 3].z, acc.z);

            acc.w = fmaf(qv.x, Wf[d4 + 0].w, acc.w);
            acc.w = fmaf(qv.y, Wf[d4 + 1].w, acc.w);
            acc.w = fmaf(qv.z, Wf[d4 + 2].w, acc.w);
            acc.w = fmaf(qv.w, Wf[d4 + 3].w, acc.w);
        }
        *(float4*)(obase + (size_t)l * DH + eg * 4) = acc;
    }
}

extern "C" void kernel_launch(void* const* d_in, const int* in_sizes, int n_in,
                              void* d_out, int out_size, void* d_ws, size_t ws_size,
                              hipStream_t stream) {
    const float* q = (const float*)d_in[0];
    const float* k = (const float*)d_in[1];
    const float* v = (const float*)d_in[2];
    float* out  = (float*)d_out;
    float* wts  = out + OUT_ELEMS;          // attn_weights region of d_out
    float* part = (float*)d_ws;             // 8 MB of partials

    kv_partial<<<BS * NH * SPLIT, 256, 0, stream>>>(k, v, part);
    softmax_b<<<HDE / 256, 256, 0, stream>>>(part, wts);
    qw<<<BS * NH * (LQ / 128), 256, 0, stream>>>(q, wts, out);
}

// Round 2
// 159.774 us; speedup vs baseline: 1.9933x; 1.9933x over previous
//
#include <hip/hip_runtime.h>

#define BS 16
#define NH 16
#define LQ 4096
#define DH 32

constexpr int SPLIT = 8;
constexpr int SCHUNK = LQ / SPLIT;          // 512 s-values per block; 128 per wave
constexpr size_t OUT_ELEMS = (size_t)BS * NH * LQ * DH;   // 33,554,432
constexpr int HDE = NH * DH * DH;           // 16384

// ---------------- Kernel A: partial K@V over an s-chunk ----------------
// 2048 blocks x 256 thr. Wave-private LDS tiles (16 KB/wave, 64 KB/block -> 2 blocks/CU).
// Lane owns a 4x4 tile of W. 2 ds_read_b128 per 16 FMA. K^T stored XOR-swizzled.
__global__ __launch_bounds__(256, 2) void kv_partial(const float* __restrict__ k,
                                                     const float* __restrict__ v,
                                                     float* __restrict__ part) {
    __shared__ float lds[4 * 4096];
    const int tid  = threadIdx.x;
    const int wid  = tid >> 6;
    const int lane = tid & 63;
    const int blk  = blockIdx.x;
    const int p    = blk & (SPLIT - 1);
    const int bh   = blk >> 3;

    float* kt = &lds[wid * 4096];        // K^T, swizzled [64 s][32 d]
    float* vt = kt + 2048;               // V, linear    [64 s][32 e]

    const int d0 = (lane >> 3) << 2;     // 0,4,..,28
    const int e0 = (lane & 7) << 2;      // 0,4,..,28

    const float* kb = k + (size_t)bh * DH * LQ;
    const float* vb = v + (size_t)bh * LQ * DH;

    const int s_base = p * SCHUNK + wid * 128;
    const int krow = lane >> 4;          // 0..3
    const int c    = lane & 15;          // s-group within stage
    const int kcol = c << 2;

    // Load both 64-s stages' K and V fragments into registers up front
    // (fully overlaps HBM latency with stage-0 LDS write + compute).
    float4 kr[2][8], vr[2][8];
#pragma unroll
    for (int st = 0; st < 2; ++st) {
        const int s0 = s_base + st * 64;
#pragma unroll
        for (int i = 0; i < 8; ++i)
            kr[st][i] = *(const float4*)(kb + (size_t)(krow + 4 * i) * LQ + s0 + kcol);
#pragma unroll
        for (int i = 0; i < 8; ++i)
            vr[st][i] = *(const float4*)(vb + (size_t)s0 * DH + ((lane + 64 * i) << 2));
    }

    float4 acc0 = {0,0,0,0}, acc1 = {0,0,0,0}, acc2 = {0,0,0,0}, acc3 = {0,0,0,0};

    const int wsw = (c & 7) << 2;        // write-side swizzle (= read's ((s>>2)&7)<<2 since s>>2 == c)

#pragma unroll
    for (int st = 0; st < 2; ++st) {
        // WAR safety on LDS reuse: all prior ds_reads have returned before new writes issue.
        asm volatile("s_waitcnt lgkmcnt(0)" ::: "memory");
        // K^T scatter (2-way max on banks with the swizzle -> free)
#pragma unroll
        for (int i = 0; i < 8; ++i) {
            const int rsw = (krow + 4 * i) ^ wsw;
            kt[(kcol + 0) * 32 + rsw] = kr[st][i].x;
            kt[(kcol + 1) * 32 + rsw] = kr[st][i].y;
            kt[(kcol + 2) * 32 + rsw] = kr[st][i].z;
            kt[(kcol + 3) * 32 + rsw] = kr[st][i].w;
        }
        // V linear (contiguous b128 writes)
#pragma unroll
        for (int i = 0; i < 8; ++i)
            *(float4*)(vt + ((lane + 64 * i) << 2)) = vr[st][i];

        // No barrier: buffers are wave-private; compiler inserts lgkmcnt before use.
#pragma unroll 8
        for (int s = 0; s < 64; ++s) {
            const int sw = ((s >> 2) & 7) << 2;
            const float4 kv = *(const float4*)(kt + s * 32 + (d0 ^ sw));
            const float4 vv = *(const float4*)(vt + s * 32 + e0);
            acc0.x = fmaf(kv.x, vv.x, acc0.x);
            acc0.y = fmaf(kv.x, vv.y, acc0.y);
            acc0.z = fmaf(kv.x, vv.z, acc0.z);
            acc0.w = fmaf(kv.x, vv.w, acc0.w);
            acc1.x = fmaf(kv.y, vv.x, acc1.x);
            acc1.y = fmaf(kv.y, vv.y, acc1.y);
            acc1.z = fmaf(kv.y, vv.z, acc1.z);
            acc1.w = fmaf(kv.y, vv.w, acc1.w);
            acc2.x = fmaf(kv.z, vv.x, acc2.x);
            acc2.y = fmaf(kv.z, vv.y, acc2.y);
            acc2.z = fmaf(kv.z, vv.z, acc2.z);
            acc2.w = fmaf(kv.z, vv.w, acc2.w);
            acc3.x = fmaf(kv.w, vv.x, acc3.x);
            acc3.y = fmaf(kv.w, vv.y, acc3.y);
            acc3.z = fmaf(kv.w, vv.z, acc3.z);
            acc3.w = fmaf(kv.w, vv.w, acc3.w);
        }
    }

    // Per-wave partial -> wave's own LDS region (linear [32 d][32 e]), then block reduce.
    asm volatile("s_waitcnt lgkmcnt(0)" ::: "memory");
    *(float4*)(kt + (d0 + 0) * 32 + e0) = acc0;
    *(float4*)(kt + (d0 + 1) * 32 + e0) = acc1;
    *(float4*)(kt + (d0 + 2) * 32 + e0) = acc2;
    *(float4*)(kt + (d0 + 3) * 32 + e0) = acc3;
    __syncthreads();

    float4 s0 = *(const float4*)(&lds[0 * 4096] + tid * 4);
    float4 s1 = *(const float4*)(&lds[1 * 4096] + tid * 4);
    float4 s2 = *(const float4*)(&lds[2 * 4096] + tid * 4);
    float4 s3 = *(const float4*)(&lds[3 * 4096] + tid * 4);
    float4 r;
    r.x = (s0.x + s1.x) + (s2.x + s3.x);
    r.y = (s0.y + s1.y) + (s2.y + s3.y);
    r.z = (s0.z + s1.z) + (s2.z + s3.z);
    r.w = (s0.w + s1.w) + (s2.w + s3.w);
    *(float4*)(part + ((size_t)p * (BS * NH) + bh) * 1024 + tid * 4) = r;
}

// ---------------- Kernel B: reduce partials + softmax over batch axis ----------------
__global__ __launch_bounds__(256) void softmax_b(const float* __restrict__ part,
                                                 float* __restrict__ wts) {
    int idx = blockIdx.x * 256 + threadIdx.x;     // 0..16383 = h*1024 + d*32 + e

    float sc[BS];
#pragma unroll
    for (int b = 0; b < BS; ++b) {
        float s = 0.f;
#pragma unroll
        for (int p = 0; p < SPLIT; ++p) {
            s += part[(((size_t)p * BS * NH + (size_t)b * NH) << 10) + idx];
        }
        sc[b] = s * (1.0f / 64.0f);               // / sqrt(4096)
    }

    float m = sc[0];
#pragma unroll
    for (int b = 1; b < BS; ++b) m = fmaxf(m, sc[b]);
    float sum = 0.f;
#pragma unroll
    for (int b = 0; b < BS; ++b) { sc[b] = __expf(sc[b] - m); sum += sc[b]; }
    float inv = 1.0f / sum;
#pragma unroll
    for (int b = 0; b < BS; ++b) {
        wts[(size_t)b * HDE + idx] = sc[b] * inv;
    }
}

// ---------------- Kernel C: out = Q @ W ----------------
// 8192 blocks x 256 thr. Q tile staged in LDS (stride 36 -> conflict-free b128 reads),
// W column-block in 128 VGPRs. 1 ds_read_b128 per 16 FMA.
__global__ __launch_bounds__(256, 2) void qw(const float* __restrict__ q,
                                             const float* __restrict__ wts,
                                             float* __restrict__ out) {
    __shared__ float qs[128 * 36];
    const int blk = blockIdx.x;
    const int bh  = blk >> 5;
    const int lt  = blk & 31;
    const int tid = threadIdx.x;

    const float* qbase = q + ((size_t)bh * LQ + lt * 128) * DH;

#pragma unroll
    for (int pp = 0; pp < 4; ++pp) {
        const int idx = pp * 256 + tid;           // float4 index 0..1023
        const int row = idx >> 3;
        const int c4  = idx & 7;
        const float4 t = *(const float4*)(qbase + idx * 4);
        *(float4*)(qs + row * 36 + c4 * 4) = t;
    }

    const int lsub = tid >> 3;                    // 0..31
    const int e0   = (tid & 7) << 2;

    float4 Wf[32];
    const float* wbase = wts + (size_t)bh * (DH * DH) + e0;
#pragma unroll
    for (int d = 0; d < 32; ++d) Wf[d] = *(const float4*)(wbase + d * DH);

    __syncthreads();

    float* obase = out + ((size_t)bh * LQ + lt * 128) * DH;

#pragma unroll
    for (int r = 0; r < 4; ++r) {
        const int lr = lsub + r * 32;
        const float* qrow = qs + lr * 36;
        float4 acc = {0,0,0,0};
#pragma unroll
        for (int d4 = 0; d4 < 32; d4 += 4) {
            const float4 qv = *(const float4*)(qrow + d4);
            acc.x = fmaf(qv.x, Wf[d4 + 0].x, acc.x);
            acc.x = fmaf(qv.y, Wf[d4 + 1].x, acc.x);
            acc.x = fmaf(qv.z, Wf[d4 + 2].x, acc.x);
            acc.x = fmaf(qv.w, Wf[d4 + 3].x, acc.x);

            acc.y = fmaf(qv.x, Wf[d4 + 0].y, acc.y);
            acc.y = fmaf(qv.y, Wf[d4 + 1].y, acc.y);
            acc.y = fmaf(qv.z, Wf[d4 + 2].y, acc.y);
            acc.y = fmaf(qv.w, Wf[d4 + 3].y, acc.y);

            acc.z = fmaf(qv.x, Wf[d4 + 0].z, acc.z);
            acc.z = fmaf(qv.y, Wf[d4 + 1].z, acc.z);
            acc.z = fmaf(qv.z, Wf[d4 + 2].z, acc.z);
            acc.z = fmaf(qv.w, Wf[d4 + 3].z, acc.z);

            acc.w = fmaf(qv.x, Wf[d4 + 0].w, acc.w);
            acc.w = fmaf(qv.y, Wf[d4 + 1].w, acc.w);
            acc.w = fmaf(qv.z, Wf[d4 + 2].w, acc.w);
            acc.w = fmaf(qv.w, Wf[d4 + 3].w, acc.w);
        }
        *(float4*)(obase + (size_t)lr * DH + e0) = acc;
    }
}

extern "C" void kernel_launch(void* const* d_in, const int* in_sizes, int n_in,
                              void* d_out, int out_size, void* d_ws, size_t ws_size,
                              hipStream_t stream) {
    const float* q = (const float*)d_in[0];
    const float* k = (const float*)d_in[1];
    const float* v = (const float*)d_in[2];
    float* out  = (float*)d_out;
    float* wts  = out + OUT_ELEMS;          // attn_weights region of d_out
    float* part = (float*)d_ws;             // 8 MB of partials

    kv_partial<<<BS * NH * SPLIT, 256, 0, stream>>>(k, v, part);
    softmax_b<<<HDE / 256, 256, 0, stream>>>(part, wts);
    qw<<<BS * NH * (LQ / 128), 256, 0, stream>>>(q, wts, out);
}